// Round 5
// baseline (889.364 us; speedup 1.0000x reference)
//
#include <hip/hip_runtime.h>
#include <stdint.h>

// Problem constants (n=1, c=32, h=w=128, p=3)
#define NPT   16384         // points (h*w)
#define KE    64            // per-point record: 32 hi f16 | 32 lo f16
#define ROWB  8192          // 128 points * KE f16 per image row

typedef _Float16 f16;
typedef __attribute__((ext_vector_type(8))) _Float16 half8;
typedef __attribute__((ext_vector_type(4))) float floatx4;

#define AS1(p) ((const __attribute__((address_space(1))) uint32_t*)(p))
#define AS3(p) ((__attribute__((address_space(3))) uint32_t*)(p))

// -------- per-pixel fp32->2xf16 split + per-pixel channel norm --------------
__global__ __launch_bounds__(256)
void extract_kernel(const float* __restrict__ src, const float* __restrict__ tgt,
                    f16* __restrict__ Aext, f16* __restrict__ Bext,
                    double* __restrict__ n2s, double* __restrict__ n2t) {
  __shared__ f16 bufA[256 * KE];   // 32 KB
  __shared__ f16 bufB[256 * KE];   // 32 KB
  const int tid = threadIdx.x;
  const int pt = blockIdx.x * 256 + tid;
  double sA = 0.0, sB = 0.0;
#pragma unroll
  for (int c = 0; c < 32; ++c) {
    float v = src[(c << 14) + pt];
    sA += (double)v * (double)v;
    f16 h = (f16)v;
    bufA[tid * KE + c] = h;
    bufA[tid * KE + 32 + c] = (f16)(v - (float)h);
    v = tgt[(c << 14) + pt];
    sB += (double)v * (double)v;
    h = (f16)v;
    bufB[tid * KE + c] = h;
    bufB[tid * KE + 32 + c] = (f16)(v - (float)h);
  }
  n2s[pt] = sA;
  n2t[pt] = sB;
  __syncthreads();
  const uint4* s4A = (const uint4*)bufA;
  const uint4* s4B = (const uint4*)bufB;
  uint4* gA = (uint4*)(Aext + (size_t)blockIdx.x * 256 * KE);
  uint4* gB = (uint4*)(Bext + (size_t)blockIdx.x * 256 * KE);
#pragma unroll
  for (int it = 0; it < 8; ++it) {
    gA[it * 256 + tid] = s4A[it * 256 + tid];
    gB[it * 256 + tid] = s4B[it * 256 + tid];
  }
}

// -------- patch norms = 9-tap clamped blur of per-pixel norms ----------------
__global__ __launch_bounds__(256)
void norm_blur_kernel(const double* __restrict__ n2s, const double* __restrict__ n2t,
                      float* __restrict__ rq, float* __restrict__ rp,
                      unsigned long long* __restrict__ best) {
  const int pt = blockIdx.x * 256 + threadIdx.x;
  const int y = pt >> 7, x = pt & 127;
  double sq = 0.0, sp_ = 0.0;
#pragma unroll
  for (int dy = -1; dy <= 1; ++dy) {
    int yy = y + dy; yy = yy < 0 ? 0 : (yy > 127 ? 127 : yy);
#pragma unroll
    for (int dx = -1; dx <= 1; ++dx) {
      int xx = x + dx; xx = xx < 0 ? 0 : (xx > 127 ? 127 : xx);
      sq  += n2s[(yy << 7) + xx];
      sp_ += n2t[(yy << 7) + xx];
    }
  }
  rq[pt] = (float)sq;
  rp[pt] = (float)sp_;
  best[pt] = 0xFFFFFFFFFFFFFFFFULL;
}

// --- MFMA GEMM (K=96, LDS-staged) + 2-phase blur/argmin ----------------------
// Session finding (rounds 0-4): occupancy tracks TOTAL regs (arch VGPR +
// AGPR acc, unified file on gfx950). VGPR_Count 124 + 64 acc = 188 -> only
// 2 waves/SIMD (22% occ). launch_bounds(256,4) caps the budget at 128 total:
// GEMM body needs ~60 arch regs (ah/al resident, bh/bl streamed — round 0
// compiled this to VGPR_Count 64, no spill), epilogue peak ~100. Expect
// 4 waves/SIMD -> MfmaUtil ~2x. Watch WRITE_SIZE for spill (round-2 trap).
__global__ __launch_bounds__(256, 4)
void gemm_blur_argmin_kernel(const f16* __restrict__ A, const f16* __restrict__ B,
                             const float* __restrict__ rq,
                             unsigned long long* __restrict__ best) {
  __shared__ __align__(16) char smem[65 * 128 * 4];  // 33.28 KB
  f16* Ash = (f16*)smem;               // [128][64] staging, 16 KB
  f16* Bsh = (f16*)(smem + 16384);     // [128][64] staging, 16 KB
  float* Cf = (float*)smem;            // [65][128] f32 (epilogue, aliased)

  // ---- supertile swizzle: L -> (bx, by) ----
  const int L  = blockIdx.x;
  const int st = L >> 7;
  const int r  = L & 127;
  const int bx = ((st & 15) << 3) | (r & 7);
  const int by = ((st >> 4) << 4) | (r >> 3);
  const int yq = by;                   // source image row (M dim)
  const int vt = bx;                   // target image row (N dim)

  const f16* Aw[3] = { A + (size_t)(yq > 0 ? yq - 1 : 0) * ROWB,
                       A + (size_t)yq * ROWB,
                       A + (size_t)(yq < 127 ? yq + 1 : 127) * ROWB };
  const f16* Bw[3] = { B + (size_t)(vt > 0 ? vt - 1 : 0) * ROWB,
                       B + (size_t)vt * ROWB,
                       B + (size_t)(vt < 127 ? vt + 1 : 127) * ROWB };

  const int t = threadIdx.x;
  const int w = t >> 6;
  const int l = t & 63;

  // ---- staging decode: 64 lanes cover 8 rows x 8 XOR-swizzled 16B slots ----
  const int lr = l >> 3;
  const int lt = l & 7;
  const int sl = lt ^ (lr & 7);
  int rowOff[4];
#pragma unroll
  for (int ig = 0; ig < 4; ++ig)
    rowOff[ig] = (w * 32 + ig * 8 + lr) * KE + sl * 8;

  // ---- fragment decode (16x16x32) ----
  const int m16 = l & 15;
  const int q   = l >> 4;
  const int pHi = q ^ (m16 & 7);
  const int pLo = pHi ^ 4;
  const int wRow = (w & 1) * 64;
  const int wCol = (w >> 1) * 64;
  const int aHiOff = m16 * 64 + pHi * 8;
  const int aLoOff = m16 * 64 + pLo * 8;

  floatx4 acc[4][4] = {};

#pragma unroll
  for (int kw = 0; kw < 3; ++kw) {
    __syncthreads();                   // previous window's LDS reads complete
#pragma unroll
    for (int ig = 0; ig < 4; ++ig)
      __builtin_amdgcn_global_load_lds(AS1(Aw[kw] + rowOff[ig]),
                                       AS3(&Ash[(w * 32 + ig * 8) * 64]), 16, 0, 0);
#pragma unroll
    for (int ig = 0; ig < 4; ++ig)
      __builtin_amdgcn_global_load_lds(AS1(Bw[kw] + rowOff[ig]),
                                       AS3(&Bsh[(w * 32 + ig * 8) * 64]), 16, 0, 0);
    __syncthreads();                   // staging drained (vmcnt0 + barrier)

    half8 ah[4], al[4];
#pragma unroll
    for (int i = 0; i < 4; ++i) {
      ah[i] = *(const half8*)&Ash[(wRow + i * 16) * 64 + aHiOff];
      al[i] = *(const half8*)&Ash[(wRow + i * 16) * 64 + aLoOff];
    }
    // per-acc order: ah*bh, al*bh, ah*bl (bit-exact vs all passing rounds)
#pragma unroll
    for (int j = 0; j < 4; ++j) {
      half8 bh = *(const half8*)&Bsh[(wCol + j * 16) * 64 + aHiOff];
#pragma unroll
      for (int i = 0; i < 4; ++i)
        acc[i][j] = __builtin_amdgcn_mfma_f32_16x16x32_f16(ah[i], bh, acc[i][j], 0, 0, 0);
#pragma unroll
      for (int i = 0; i < 4; ++i)
        acc[i][j] = __builtin_amdgcn_mfma_f32_16x16x32_f16(al[i], bh, acc[i][j], 0, 0, 0);
    }
#pragma unroll
    for (int j = 0; j < 4; ++j) {
      half8 bl = *(const half8*)&Bsh[(wCol + j * 16) * 64 + aLoOff];
#pragma unroll
      for (int i = 0; i < 4; ++i)
        acc[i][j] = __builtin_amdgcn_mfma_f32_16x16x32_f16(ah[i], bl, acc[i][j], 0, 0, 0);
    }
  }
  __syncthreads();                     // staging readers done; Cf aliases Ash/Bsh

  // ---- 2-phase epilogue: spill 65 rows, blur+argmin 64 output rows ----
  // C/D layout (16x16): col = lane&15 (+wCol+j*16), row = q*4 + r2 (+wRow+i*16)
#define SWZ(row, col) (((row) << 7) + ((((col) >> 2) ^ ((row) & 7)) << 2) + ((col) & 3))
#define LDCF(row, g) (*(const floatx4*)&Cf[((row) << 7) + ((((g) ^ ((row) & 7))) << 2)])

  const int xr_l = t >> 2;             // 0..63 output row within phase
  const int uq = t & 3;                // col quarter (32 cols)
  const int g0 = uq << 3;              // first float4 group of 8
  const floatx4* rq4 = (const floatx4*)(rq + (vt << 7));

#pragma unroll
  for (int ph = 0; ph < 2; ++ph) {
    // ---- spill: owning wave-pair writes 64 rows; other pair writes halo ----
    if ((ph == 0) ? (wRow == 0) : (wRow == 64)) {
      const int rbase = ph;            // phase B: global row 64+k -> local 1+k
#pragma unroll
      for (int i = 0; i < 4; ++i)
#pragma unroll
        for (int j = 0; j < 4; ++j) {
          const int col = wCol + j * 16 + m16;
#pragma unroll
          for (int r2 = 0; r2 < 4; ++r2) {
            const int lrow = rbase + i * 16 + q * 4 + r2;
            Cf[SWZ(lrow, col)] = acc[i][j][r2];
          }
        }
    } else if ((ph == 0) ? (q == 0) : (q == 3)) {
      // halo: phase A needs global row 64 (waves wRow=64: i=0,q=0,r2=0);
      //       phase B needs global row 63 (waves wRow=0: i=3,q=3,r2=3)
      const int lrow = ph ? 0 : 64;
#pragma unroll
      for (int j = 0; j < 4; ++j) {
        const int col = wCol + j * 16 + m16;
        Cf[SWZ(lrow, col)] = ph ? acc[3][j][3] : acc[0][j][0];
      }
    }
    __syncthreads();

    const int x   = ph * 64 + xr_l;    // global output row
    const int lx  = ph ? xr_l + 1 : xr_l;
    const int lxm = ph ? lx - 1 : (xr_l ? xr_l - 1 : 0);
    const int lxp = (ph && x == 127) ? lx : lx + 1;

    float bf = __builtin_huge_valf();
    int bu = 0;
    float am_last = (uq == 0) ? LDCF(lxm, 0)[0] : LDCF(lxm, g0 - 1)[3];
    floatx4 Ap = LDCF(lxp, g0);
#pragma unroll
    for (int k = 0; k < 8; ++k) {
      const int g = g0 + k;
      const floatx4 Am = LDCF(lxm, g);
      const floatx4 Ac = LDCF(lx, g);
      floatx4 ApN = Ap;
      float ap4;
      if (k < 7)       { ApN = LDCF(lxp, g + 1); ap4 = ApN[0]; }
      else if (uq < 3) { ap4 = LDCF(lxp, g + 1)[0]; }
      else             { ap4 = Ap[3]; }          // u=127: cx(u+1)=127
      const floatx4 rv = rq4[g];
      float o0 = am_last + Ac[0] + Ap[1];
      float o1 = Am[0]   + Ac[1] + Ap[2];
      float o2 = Am[1]   + Ac[2] + Ap[3];
      float o3 = Am[2]   + Ac[3] + ap4;
      am_last = Am[3];
      Ap = ApN;
      const int ub = g << 2;
      float f0 = fmaf(-2.0f, o0, rv[0]); if (f0 < bf) { bf = f0; bu = ub; }
      float f1 = fmaf(-2.0f, o1, rv[1]); if (f1 < bf) { bf = f1; bu = ub + 1; }
      float f2 = fmaf(-2.0f, o2, rv[2]); if (f2 < bf) { bf = f2; bu = ub + 2; }
      float f3 = fmaf(-2.0f, o3, rv[3]); if (f3 < bf) { bf = f3; bu = ub + 3; }
    }
    unsigned int bits = __float_as_uint(bf);
    unsigned int key = (bits & 0x80000000u) ? ~bits : (bits | 0x80000000u);
    unsigned long long pk =
        ((unsigned long long)key << 32) | (unsigned)((vt << 7) + bu);
    unsigned long long o1v = __shfl_xor(pk, 1); pk = pk < o1v ? pk : o1v;
    unsigned long long o2v = __shfl_xor(pk, 2); pk = pk < o2v ? pk : o2v;
    if (uq == 0) atomicMin(best + (yq << 7) + x, pk);
    if (ph == 0) __syncthreads();      // Cf reused by phase B
  }
#undef SWZ
#undef LDCF
}

// ---------------------------- finalize ---------------------------------------
__global__ void finalize_kernel(const unsigned long long* __restrict__ best,
                                const float* __restrict__ rp,
                                float* __restrict__ out) {
  int i = blockIdx.x * 256 + threadIdx.x;
  if (i >= NPT) return;
  unsigned long long v = best[i];
  unsigned int col = (unsigned int)(v & 0xFFFFFFFFu);
  unsigned int key = (unsigned int)(v >> 32);
  unsigned int bits = (key & 0x80000000u) ? (key & 0x7FFFFFFFu) : ~key;
  float fmin = __uint_as_float(bits);
  out[i]           = (float)(col >> 7);   // idy
  out[NPT + i]     = (float)(col & 127);  // idx
  out[2 * NPT + i] = rp[i] + fmin;        // nnd
}

extern "C" void kernel_launch(void* const* d_in, const int* in_sizes, int n_in,
                              void* d_out, int out_size, void* d_ws, size_t ws_size,
                              hipStream_t stream) {
  const float* src = (const float*)d_in[0];  // source_map (1,32,128,128)
  const float* tgt = (const float*)d_in[1];  // target_map (1,32,128,128)
  float* out = (float*)d_out;

  // workspace layout (bytes):
  //   Aext: [0, 2097152)        16384 x 64 f16 [hi32|lo32]
  //   Bext: [2097152, 4194304)
  //   n2s : [4194304, 4325376)  16384 f64 per-pixel channel norms (src)
  //   n2t : [4325376, 4456448)
  //   rq  : [4456448, 4521984)  16384 fp32 patch norms (src)
  //   rp  : [4521984, 4587520)
  //   best: [4587520, 4718592)  16384 u64 packed (key<<32)|col
  char* ws = (char*)d_ws;
  f16* Aext = (f16*)(ws);
  f16* Bext = (f16*)(ws + 2097152);
  double* n2s = (double*)(ws + 4194304);
  double* n2t = (double*)(ws + 4325376);
  float* rq = (float*)(ws + 4456448);
  float* rp = (float*)(ws + 4521984);
  unsigned long long* best = (unsigned long long*)(ws + 4587520);

  extract_kernel<<<64, 256, 0, stream>>>(src, tgt, Aext, Bext, n2s, n2t);
  norm_blur_kernel<<<64, 256, 0, stream>>>(n2s, n2t, rq, rp, best);
  gemm_blur_argmin_kernel<<<16384, 256, 0, stream>>>(Aext, Bext, rq, best);
  finalize_kernel<<<NPT / 256, 256, 0, stream>>>(best, rp, out);
}

// Round 6
// 305.117 us; speedup vs baseline: 2.9148x; 2.9148x over previous
//
#include <hip/hip_runtime.h>
#include <stdint.h>

// Problem constants (n=1, c=32, h=w=128, p=3)
#define NPT   16384         // points (h*w)
#define KE    64            // per-point record: 32 hi f16 | 32 lo f16
#define ROWB  8192          // 128 points * KE f16 per image row

typedef _Float16 f16;
typedef __attribute__((ext_vector_type(8))) _Float16 half8;
typedef __attribute__((ext_vector_type(4))) float floatx4;

#define AS1(p) ((const __attribute__((address_space(1))) uint32_t*)(p))
#define AS3(p) ((__attribute__((address_space(3))) uint32_t*)(p))

// -------- per-pixel fp32->2xf16 split + per-pixel channel norm --------------
__global__ __launch_bounds__(256)
void extract_kernel(const float* __restrict__ src, const float* __restrict__ tgt,
                    f16* __restrict__ Aext, f16* __restrict__ Bext,
                    double* __restrict__ n2s, double* __restrict__ n2t) {
  __shared__ f16 bufA[256 * KE];   // 32 KB
  __shared__ f16 bufB[256 * KE];   // 32 KB
  const int tid = threadIdx.x;
  const int pt = blockIdx.x * 256 + tid;
  double sA = 0.0, sB = 0.0;
#pragma unroll
  for (int c = 0; c < 32; ++c) {
    float v = src[(c << 14) + pt];
    sA += (double)v * (double)v;
    f16 h = (f16)v;
    bufA[tid * KE + c] = h;
    bufA[tid * KE + 32 + c] = (f16)(v - (float)h);
    v = tgt[(c << 14) + pt];
    sB += (double)v * (double)v;
    h = (f16)v;
    bufB[tid * KE + c] = h;
    bufB[tid * KE + 32 + c] = (f16)(v - (float)h);
  }
  n2s[pt] = sA;
  n2t[pt] = sB;
  __syncthreads();
  const uint4* s4A = (const uint4*)bufA;
  const uint4* s4B = (const uint4*)bufB;
  uint4* gA = (uint4*)(Aext + (size_t)blockIdx.x * 256 * KE);
  uint4* gB = (uint4*)(Bext + (size_t)blockIdx.x * 256 * KE);
#pragma unroll
  for (int it = 0; it < 8; ++it) {
    gA[it * 256 + tid] = s4A[it * 256 + tid];
    gB[it * 256 + tid] = s4B[it * 256 + tid];
  }
}

// -------- patch norms = 9-tap clamped blur of per-pixel norms ----------------
__global__ __launch_bounds__(256)
void norm_blur_kernel(const double* __restrict__ n2s, const double* __restrict__ n2t,
                      float* __restrict__ rq, float* __restrict__ rp,
                      unsigned long long* __restrict__ best) {
  const int pt = blockIdx.x * 256 + threadIdx.x;
  const int y = pt >> 7, x = pt & 127;
  double sq = 0.0, sp_ = 0.0;
#pragma unroll
  for (int dy = -1; dy <= 1; ++dy) {
    int yy = y + dy; yy = yy < 0 ? 0 : (yy > 127 ? 127 : yy);
#pragma unroll
    for (int dx = -1; dx <= 1; ++dx) {
      int xx = x + dx; xx = xx < 0 ? 0 : (xx > 127 ? 127 : xx);
      sq  += n2s[(yy << 7) + xx];
      sp_ += n2t[(yy << 7) + xx];
    }
  }
  rq[pt] = (float)sq;
  rp[pt] = (float)sp_;
  best[pt] = 0xFFFFFFFFFFFFFFFFULL;
}

// --- 8-wave MFMA GEMM (K=96, dbuf staging, counted vmcnt) + blur/argmin ------
// Session reg model (r0-r5): occupancy tracks TOTAL regs (arch+acc, unified
// file). acc=64/wave makes 4 waves/SIMD impossible (live set ~140 -> spill
// catastrophe r2/r5). Fix: 8 waves x (64x32 tile) -> acc[4][2]=32 regs,
// K-loop live ~87 <= 128 -> 4 waves/SIMD clean. Staging double-buffered
// (A0B0/A1B1) with counted s_waitcnt vmcnt(4) + raw s_barrier so window k+1
// loads fly under window k's MFMA (24 MFMA/window/wave is too short to hide
// L2 latency without prefetch).
__global__ __launch_bounds__(512, 4)
void gemm_blur_argmin_kernel(const f16* __restrict__ A, const f16* __restrict__ B,
                             const float* __restrict__ rq,
                             unsigned long long* __restrict__ best) {
  __shared__ __align__(16) char smem[65536];
  f16* As0 = (f16*)smem;                // buf0 A [128][64], 16 KB
  f16* Bs0 = (f16*)(smem + 16384);      // buf0 B
  f16* As1 = (f16*)(smem + 32768);      // buf1 A
  f16* Bs1 = (f16*)(smem + 49152);      // buf1 B
  float* Cf = (float*)smem;             // [65][128] f32 epilogue (aliased)

  // ---- supertile swizzle: L -> (bx, by) ----
  const int L  = blockIdx.x;
  const int st = L >> 7;
  const int r  = L & 127;
  const int bx = ((st & 15) << 3) | (r & 7);
  const int by = ((st >> 4) << 4) | (r >> 3);
  const int yq = by;                   // source image row (M dim)
  const int vt = bx;                   // target image row (N dim)

  // window rows, pinned scalar (uniform) to keep them out of the VGPR budget
  const int ym = __builtin_amdgcn_readfirstlane(yq > 0 ? yq - 1 : 0);
  const int yc = __builtin_amdgcn_readfirstlane(yq);
  const int yp = __builtin_amdgcn_readfirstlane(yq < 127 ? yq + 1 : 127);
  const int vm = __builtin_amdgcn_readfirstlane(vt > 0 ? vt - 1 : 0);
  const int vc = __builtin_amdgcn_readfirstlane(vt);
  const int vp = __builtin_amdgcn_readfirstlane(vt < 127 ? vt + 1 : 127);

  const int t = threadIdx.x;
  const int w = t >> 6;                // wave 0..7
  const int l = t & 63;

  // ---- staging decode: wave w stages rows [w*16, w*16+16) of A and B ----
  // 64 lanes cover 8 rows x 8 XOR-swizzled 16B slots per issue.
  const int lr = l >> 3;
  const int lt = l & 7;
  const int sl = lt ^ (lr & 7);        // logical slice this lane fetches
  int rowOff[2];
  rowOff[0] = (w * 16 + lr) * KE + sl * 8;
  rowOff[1] = rowOff[0] + 8 * KE;

#define STAGEW(Arow, Brow, Ad, Bd)                                             \
  { const f16* Ag = A + (size_t)(Arow) * ROWB;                                 \
    const f16* Bg = B + (size_t)(Brow) * ROWB;                                 \
    __builtin_amdgcn_global_load_lds(AS1(Ag + rowOff[0]),                      \
                                     AS3(&Ad[(w * 16) * 64]), 16, 0, 0);       \
    __builtin_amdgcn_global_load_lds(AS1(Ag + rowOff[1]),                      \
                                     AS3(&Ad[(w * 16 + 8) * 64]), 16, 0, 0);   \
    __builtin_amdgcn_global_load_lds(AS1(Bg + rowOff[0]),                      \
                                     AS3(&Bd[(w * 16) * 64]), 16, 0, 0);       \
    __builtin_amdgcn_global_load_lds(AS1(Bg + rowOff[1]),                      \
                                     AS3(&Bd[(w * 16 + 8) * 64]), 16, 0, 0); }

  // ---- fragment decode (16x16x32): wave owns 64x32 output ----
  const int m16 = l & 15;
  const int q   = l >> 4;
  const int pHi = q ^ (m16 & 7);
  const int pLo = pHi ^ 4;
  const int wRow = (w & 1) * 64;
  const int wCol = (w >> 1) * 32;
  const int aHiOff = m16 * 64 + pHi * 8;
  const int aLoOff = m16 * 64 + pLo * 8;

  floatx4 acc[4][2] = {};

  // per-acc order: ah*bh, al*bh, ah*bl per window (bit-exact vs all rounds)
#define COMPUTEW(Asb, Bsb)                                                     \
  { half8 ah[4], al[4];                                                        \
    _Pragma("unroll") for (int i = 0; i < 4; ++i) {                            \
      ah[i] = *(const half8*)&Asb[(wRow + i * 16) * 64 + aHiOff];              \
      al[i] = *(const half8*)&Asb[(wRow + i * 16) * 64 + aLoOff];              \
    }                                                                          \
    _Pragma("unroll") for (int j = 0; j < 2; ++j) {                            \
      half8 bh = *(const half8*)&Bsb[(wCol + j * 16) * 64 + aHiOff];           \
      _Pragma("unroll") for (int i = 0; i < 4; ++i)                            \
        acc[i][j] = __builtin_amdgcn_mfma_f32_16x16x32_f16(ah[i], bh, acc[i][j], 0, 0, 0); \
      _Pragma("unroll") for (int i = 0; i < 4; ++i)                            \
        acc[i][j] = __builtin_amdgcn_mfma_f32_16x16x32_f16(al[i], bh, acc[i][j], 0, 0, 0); \
    }                                                                          \
    _Pragma("unroll") for (int j = 0; j < 2; ++j) {                            \
      half8 bl = *(const half8*)&Bsb[(wCol + j * 16) * 64 + aLoOff];           \
      _Pragma("unroll") for (int i = 0; i < 4; ++i)                            \
        acc[i][j] = __builtin_amdgcn_mfma_f32_16x16x32_f16(ah[i], bl, acc[i][j], 0, 0, 0); \
    } }

  // ---- pipelined schedule: w0->buf0, w1->buf1, w2->buf0 (counted vmcnt) ----
  STAGEW(ym, vm, As0, Bs0);            // 4 loads in flight
  STAGEW(yc, vc, As1, Bs1);            // 8 in flight
  asm volatile("s_waitcnt vmcnt(4)" ::: "memory");   // w0 landed (this wave)
  __builtin_amdgcn_s_barrier();                       // ...and all waves
  COMPUTEW(As0, Bs0);
  __builtin_amdgcn_s_barrier();        // all waves done reading buf0
  STAGEW(yp, vp, As0, Bs0);            // w2 -> buf0 (w1 + w2 in flight)
  asm volatile("s_waitcnt vmcnt(4)" ::: "memory");   // w1 landed
  __builtin_amdgcn_s_barrier();
  COMPUTEW(As1, Bs1);
  asm volatile("s_waitcnt vmcnt(0)" ::: "memory");   // w2 landed
  __builtin_amdgcn_s_barrier();
  COMPUTEW(As0, Bs0);
  __builtin_amdgcn_s_barrier();        // staging readers done; Cf aliases

  // ---- 2-phase epilogue: spill 65 rows, blur+argmin 64 output rows ----
  // C/D layout (16x16): col = lane&15 (+wCol+j*16), row = q*4 + r2 (+wRow+i*16)
#define SWZ(row, col) (((row) << 7) + ((((col) >> 2) ^ ((row) & 7)) << 2) + ((col) & 3))
#define LDCF(row, g) (*(const floatx4*)&Cf[((row) << 7) + ((((g) ^ ((row) & 7))) << 2)])

  const int xr_l = t >> 3;             // 0..63 output row within phase
  const int uo = t & 7;                // 16-col strip
  const int g0 = uo << 2;              // first float4 group of 4
  const floatx4* rq4 = (const floatx4*)(rq + (vt << 7));

#pragma unroll
  for (int ph = 0; ph < 2; ++ph) {
    // ---- spill: owning waves write 64 rows; opposite waves write halo ----
    if ((ph == 0) ? (wRow == 0) : (wRow == 64)) {
      const int rbase = ph;            // phase B: global row 64+k -> local 1+k
#pragma unroll
      for (int i = 0; i < 4; ++i)
#pragma unroll
        for (int j = 0; j < 2; ++j) {
          const int col = wCol + j * 16 + m16;
#pragma unroll
          for (int r2 = 0; r2 < 4; ++r2) {
            const int lrow = rbase + i * 16 + q * 4 + r2;
            Cf[SWZ(lrow, col)] = acc[i][j][r2];
          }
        }
    } else if ((ph == 0) ? (q == 0) : (q == 3)) {
      // halo: phase A needs global row 64 (waves wRow=64: i=0,q=0,r2=0);
      //       phase B needs global row 63 (waves wRow=0: i=3,q=3,r2=3)
      const int lrow = ph ? 0 : 64;
#pragma unroll
      for (int j = 0; j < 2; ++j) {
        const int col = wCol + j * 16 + m16;
        Cf[SWZ(lrow, col)] = ph ? acc[3][j][3] : acc[0][j][0];
      }
    }
    __syncthreads();

    const int x   = ph * 64 + xr_l;    // global output row
    const int lx  = ph ? xr_l + 1 : xr_l;
    const int lxm = ph ? lx - 1 : (xr_l ? xr_l - 1 : 0);
    const int lxp = (ph && x == 127) ? lx : lx + 1;

    float bf = __builtin_huge_valf();
    int bu = 0;
    float am_last = (uo == 0) ? LDCF(lxm, 0)[0] : LDCF(lxm, g0 - 1)[3];
    floatx4 Ap = LDCF(lxp, g0);
#pragma unroll
    for (int k = 0; k < 4; ++k) {
      const int g = g0 + k;
      const floatx4 Am = LDCF(lxm, g);
      const floatx4 Ac = LDCF(lx, g);
      floatx4 ApN = Ap;
      float ap4;
      if (k < 3)       { ApN = LDCF(lxp, g + 1); ap4 = ApN[0]; }
      else if (uo < 7) { ap4 = LDCF(lxp, g + 1)[0]; }
      else             { ap4 = Ap[3]; }          // u=127: cx(u+1)=127
      const floatx4 rv = rq4[g];
      float o0 = am_last + Ac[0] + Ap[1];
      float o1 = Am[0]   + Ac[1] + Ap[2];
      float o2 = Am[1]   + Ac[2] + Ap[3];
      float o3 = Am[2]   + Ac[3] + ap4;
      am_last = Am[3];
      Ap = ApN;
      const int ub = g << 2;
      float f0 = fmaf(-2.0f, o0, rv[0]); if (f0 < bf) { bf = f0; bu = ub; }
      float f1 = fmaf(-2.0f, o1, rv[1]); if (f1 < bf) { bf = f1; bu = ub + 1; }
      float f2 = fmaf(-2.0f, o2, rv[2]); if (f2 < bf) { bf = f2; bu = ub + 2; }
      float f3 = fmaf(-2.0f, o3, rv[3]); if (f3 < bf) { bf = f3; bu = ub + 3; }
    }
    unsigned int bits = __float_as_uint(bf);
    unsigned int key = (bits & 0x80000000u) ? ~bits : (bits | 0x80000000u);
    unsigned long long pk =
        ((unsigned long long)key << 32) | (unsigned)((vt << 7) + bu);
    unsigned long long o1v = __shfl_xor(pk, 1); pk = pk < o1v ? pk : o1v;
    unsigned long long o2v = __shfl_xor(pk, 2); pk = pk < o2v ? pk : o2v;
    unsigned long long o4v = __shfl_xor(pk, 4); pk = pk < o4v ? pk : o4v;
    if (uo == 0) atomicMin(best + (yq << 7) + x, pk);
    if (ph == 0) __syncthreads();      // Cf reused by phase B
  }
#undef SWZ
#undef LDCF
}

// ---------------------------- finalize ---------------------------------------
__global__ void finalize_kernel(const unsigned long long* __restrict__ best,
                                const float* __restrict__ rp,
                                float* __restrict__ out) {
  int i = blockIdx.x * 256 + threadIdx.x;
  if (i >= NPT) return;
  unsigned long long v = best[i];
  unsigned int col = (unsigned int)(v & 0xFFFFFFFFu);
  unsigned int key = (unsigned int)(v >> 32);
  unsigned int bits = (key & 0x80000000u) ? (key & 0x7FFFFFFFu) : ~key;
  float fmin = __uint_as_float(bits);
  out[i]           = (float)(col >> 7);   // idy
  out[NPT + i]     = (float)(col & 127);  // idx
  out[2 * NPT + i] = rp[i] + fmin;        // nnd
}

extern "C" void kernel_launch(void* const* d_in, const int* in_sizes, int n_in,
                              void* d_out, int out_size, void* d_ws, size_t ws_size,
                              hipStream_t stream) {
  const float* src = (const float*)d_in[0];  // source_map (1,32,128,128)
  const float* tgt = (const float*)d_in[1];  // target_map (1,32,128,128)
  float* out = (float*)d_out;

  // workspace layout (bytes):
  //   Aext: [0, 2097152)        16384 x 64 f16 [hi32|lo32]
  //   Bext: [2097152, 4194304)
  //   n2s : [4194304, 4325376)  16384 f64 per-pixel channel norms (src)
  //   n2t : [4325376, 4456448)
  //   rq  : [4456448, 4521984)  16384 fp32 patch norms (src)
  //   rp  : [4521984, 4587520)
  //   best: [4587520, 4718592)  16384 u64 packed (key<<32)|col
  char* ws = (char*)d_ws;
  f16* Aext = (f16*)(ws);
  f16* Bext = (f16*)(ws + 2097152);
  double* n2s = (double*)(ws + 4194304);
  double* n2t = (double*)(ws + 4325376);
  float* rq = (float*)(ws + 4456448);
  float* rp = (float*)(ws + 4521984);
  unsigned long long* best = (unsigned long long*)(ws + 4587520);

  extract_kernel<<<64, 256, 0, stream>>>(src, tgt, Aext, Bext, n2s, n2t);
  norm_blur_kernel<<<64, 256, 0, stream>>>(n2s, n2t, rq, rp, best);
  gemm_blur_argmin_kernel<<<16384, 512, 0, stream>>>(Aext, Bext, rq, best);
  finalize_kernel<<<NPT / 256, 256, 0, stream>>>(best, rp, out);
}